// Round 7
// baseline (159.599 us; speedup 1.0000x reference)
//
#include <hip/hip_runtime.h>

// LSGA fused kernel, round 7: critical-path reduction.
//  - OUT = Wov·xbar + (Wov·W2^T)·hbar + bov2  (W2T phase + barrier gone)
//  - e0[n] = su2·x_n + d0b (precomputed su2 = Wq^T(t+bk), t = Wk·b2; d0b = bq·(t+bk))
//  - softmax done in-wave via shfl_xor(16/32) on the score D-fragment
//  - scores gather rows prefetched into registers in the preamble
//  - XCD swizzle: batch = blockIdx&1 -> per-XCD L2 caches one batch's xT
//  4 barriers/block (was 7), ~18 KB LDS, __launch_bounds__(256,4).
//
// MFMA 16x16x32 lane mappings (verified rounds 3-6):
//   A-frag:  A[m = lane&15][k = (lane>>4)*8 + j]
//   B-frag:  B[k = (lane>>4)*8 + j][n = lane&15]
//   C/D:     col = lane&15, row = (lane>>4)*4 + reg

using u16 = unsigned short;
using u32 = unsigned int;
using u64 = unsigned long long;

typedef short bf16x8 __attribute__((ext_vector_type(8)));
typedef float f32x4  __attribute__((ext_vector_type(4)));

__device__ __forceinline__ float bl(u32 u) { return __uint_as_float(u << 16); }
__device__ __forceinline__ float bh(u32 u) { return __uint_as_float(u & 0xffff0000u); }
__device__ __forceinline__ float b2f(u16 u) { return __uint_as_float(((u32)u) << 16); }
__device__ __forceinline__ u16 f2b(float f) {
    u32 u = __float_as_uint(f);
    u32 r = u + 0x7fffu + ((u >> 16) & 1u);   // RNE
    return (u16)(r >> 16);
}
__device__ __forceinline__ float dot8(uint4 wv, const float* xp) {
    float4 a = *(const float4*)xp;
    float4 b = *(const float4*)(xp + 4);
    return bl(wv.x)*a.x + bh(wv.x)*a.y + bl(wv.y)*a.z + bh(wv.y)*a.w
         + bl(wv.z)*b.x + bh(wv.z)*b.y + bl(wv.w)*b.z + bh(wv.w)*b.w;
}
__device__ __forceinline__ u64 pack4(float a, float b, float c, float d) {
    return (u64)f2b(a) | ((u64)f2b(b) << 16) | ((u64)f2b(c) << 32) | ((u64)f2b(d) << 48);
}
// A-operand frag flat index for element [m][c] of a 128-col operand
__device__ __forceinline__ int fidxA(int m, int c) {
    return (((m >> 4)*4 + (c >> 5))*64 + ((c >> 3) & 3)*16 + (m & 15))*8 + (c & 7);
}

// ---------------------------------------------------------------------------
// Kernel 1 (merged): blocks 0..129 weight fuse/pack, 130..2177 transpose.
__global__ void __launch_bounds__(512)
k_pt(const float* __restrict__ x,
     const float* __restrict__ Wq, const float* __restrict__ bq,
     const float* __restrict__ Wk, const float* __restrict__ bk,
     const float* __restrict__ Wv, const float* __restrict__ bv,
     const float* __restrict__ Wo, const float* __restrict__ bo,
     const float* __restrict__ W1, const float* __restrict__ W2,
     const float* __restrict__ b2,
     u16* __restrict__ Afrag, u16* __restrict__ Wovfrag,
     u16* __restrict__ W1frag, u16* __restrict__ W2frag,
     u16* __restrict__ Wovt2frag,
     float* __restrict__ bA, float* __restrict__ su2,
     float* __restrict__ bov2, float* __restrict__ d0b,
     u16* __restrict__ xT)
{
    const int blk = blockIdx.x, tid = threadIdx.x;

    if (blk >= 130) {
        // ---- transpose x[b][c][n] -> xT[b][n][c] (bf16), 32x32 tiles ----
        __shared__ u16 tile[32][33];
        const int blk2 = blk - 130;
        const int b  = blk2 >> 10;
        const int ct = (blk2 >> 8) & 3;
        const int nt = blk2 & 255;
        const int tx = tid & 31, ty = tid >> 5;      // 32 x 16
        const size_t xb = (size_t)b * 128 * 8192;
        #pragma unroll
        for (int j = 0; j < 2; ++j) {
            int c = ct*32 + ty + j*16;
            tile[ty + j*16][tx] = f2b(x[xb + (size_t)c * 8192 + (size_t)(nt*32 + tx)]);
        }
        __syncthreads();
        #pragma unroll
        for (int j = 0; j < 2; ++j) {
            int n = nt*32 + ty + j*16;
            xT[xb + (size_t)n * 128 + (size_t)(ct*32 + tx)] = tile[tx][ty + j*16];
        }
        return;
    }

    const int i = tid & 127, p = tid >> 7;          // 4-way K-split
    if (blk < 128) {
        __shared__ float sWk[128], sWo[128];
        __shared__ float s_pA[4][128], s_pV[4][128];
        __shared__ float s_row[128];
        if (tid < 128) sWk[tid] = Wk[tid*128 + blk];
        else if (tid < 256) sWo[tid-128] = Wo[blk*128 + (tid-128)];
        __syncthreads();
        float accA = 0.f, accV = 0.f;
        #pragma unroll 8
        for (int o = p*32; o < p*32 + 32; ++o) {
            accA += sWk[o] * Wq[o*128 + i];
            accV += sWo[o] * Wv[o*128 + i];
        }
        s_pA[p][i] = accA; s_pV[p][i] = accV;
        __syncthreads();
        if (tid < 128) {
            float v = s_pA[0][tid] + s_pA[1][tid] + s_pA[2][tid] + s_pA[3][tid];
            Afrag[fidxA(blk, tid)] = f2b(v);
        } else if (tid < 256) {
            int ii = tid - 128;
            float v = s_pV[0][ii] + s_pV[1][ii] + s_pV[2][ii] + s_pV[3][ii];
            Wovfrag[fidxA(blk, ii)] = f2b(v);
            s_row[ii] = v;
        }
        __syncthreads();
        if (tid < 32) {
            // Wovt2[blk][m] = sum_c Wov[blk][c] * W2[m][c]; A-frag (K=32)
            float wv2 = 0.f;
            for (int c = 0; c < 128; ++c) wv2 += s_row[c] * W2[tid*128 + c];
            Wovt2frag[(((blk >> 4)*64) + (tid >> 3)*16 + (blk & 15))*8 + (tid & 7)] = f2b(wv2);
        } else if (tid == 32) {
            float rb2 = 0.f, a3 = 0.f;
            for (int c = 0; c < 128; ++c) rb2 += s_row[c] * b2[c];
            for (int o = 0; o < 128; ++o) a3 += sWo[o] * bv[o];
            bov2[blk] = rb2 + a3 + bo[blk];
        }
    } else if (blk == 128) {
        __shared__ float s_t[128];
        __shared__ float s_p1[4][128], s_p2[4][128];
        if (tid < 128) {
            float tt = 0.f;
            for (int c = 0; c < 128; ++c) tt += Wk[tid*128 + c] * b2[c];
            s_t[tid] = tt + bk[tid];          // t[o] + bk[o]
        }
        __syncthreads();
        float a1 = 0.f, a2 = 0.f;
        #pragma unroll 8
        for (int o = p*32; o < p*32 + 32; ++o) {
            a1 += Wk[o*128 + i] * bq[o];       // bA
            a2 += Wq[o*128 + i] * s_t[o];      // su2
        }
        s_p1[p][i] = a1; s_p2[p][i] = a2;
        __syncthreads();
        if (tid < 128) {
            bA[tid] = s_p1[0][tid] + s_p1[1][tid] + s_p1[2][tid] + s_p1[3][tid];
        } else if (tid < 256) {
            int ii = tid - 128;
            su2[ii] = s_p2[0][ii] + s_p2[1][ii] + s_p2[2][ii] + s_p2[3][ii];
        } else if (tid < 320) {
            int l = tid - 256;                 // one wave: d0b = bq·(t+bk)
            float part = bq[l]*s_t[l] + bq[l+64]*s_t[l+64];
            part += __shfl_xor(part, 1);
            part += __shfl_xor(part, 2);
            part += __shfl_xor(part, 4);
            part += __shfl_xor(part, 8);
            part += __shfl_xor(part, 16);
            part += __shfl_xor(part, 32);
            if (l == 0) *d0b = part;
        }
    } else {
        // blk == 129: fragment packs for W1 / W2
        for (int e = tid; e < 4096; e += 512) {
            int ii = e & 127, r2 = e >> 7;         // r2 in [0,32)
            {   // W1frag: B-operand of H=E*W1, elem B[k=ii][n=r2]
                int nt = r2 >> 4, lmm = r2 & 15;
                int ks = ii >> 5, q = (ii >> 3) & 3, j = ii & 7;
                W1frag[((nt*4 + ks)*64 + q*16 + lmm)*8 + j] = f2b(W1[ii*32 + r2]);
            }
            {   // W2frag: A-operand of G=W2*QK, elem A[m=r2][c=ii]
                int mt = r2 >> 4, lmm = r2 & 15;
                int ks = ii >> 5, q = (ii >> 3) & 3, j = ii & 7;
                W2frag[((mt*4 + ks)*64 + q*16 + lmm)*8 + j] = f2b(W2[r2*128 + ii]);
            }
        }
    }
}

// ---------------------------------------------------------------------------
// Kernel 2: fused main. Grid 2048 x 256; 8 n per block; 4 barriers; ~18 KB LDS.
__global__ void __launch_bounds__(256, 4)
k_main(const u16* __restrict__ xT, const float* __restrict__ coords,
       const int* __restrict__ idx, const float* __restrict__ Bg,
       const float* __restrict__ b1g,
       const u16* __restrict__ Afrag, const u16* __restrict__ Wovfrag,
       const u16* __restrict__ W1frag, const u16* __restrict__ W2frag,
       const u16* __restrict__ Wovt2frag,
       const float* __restrict__ bAg, const float* __restrict__ su2g,
       const float* __restrict__ bov2g, const float* __restrict__ d0bg,
       float* __restrict__ out)
{
    __shared__ __align__(16) u16   sH[128][40];      // H bf16 rows (n,k) x m
    __shared__ __align__(16) u16   s_qkb[8][136];    // qk bf16 [n][c]
    __shared__ __align__(16) u16   s_gb[8][40];      // g bf16 [n][m]
    __shared__ __align__(16) u16   s_xb[8][136];     // xbar bf16 [n][c]
    __shared__ __align__(16) u16   sHbarT[8][40];    // hbar bf16 [n][m]
    __shared__ float s_attn[8][17];
    __shared__ float s_e0[8];
    __shared__ __align__(16) float sBgT[64][4];
    __shared__ int s_idx[128];

    const int tid = threadIdx.x;
    const int w = tid >> 6, l = tid & 63, lm = l & 15, lq = l >> 4, lmm = lm & 7;
    // XCD swizzle: batch = blk&1 (even blocks -> XCDs 0/2/4/6), chunk = blk>>1
    const int bsel = blockIdx.x & 1;
    const int n0 = (blockIdx.x >> 1) * 8;
    const int g0 = (bsel << 13) + n0;
    const size_t bbase = ((size_t)bsel) << 13;
    const float inv_sqrtC = 0.08838834764831845f;

    sBgT[tid >> 2][tid & 3] = Bg[(tid & 3)*64 + (tid >> 2)];
    const float c_d0b = *d0bg;

    // ---- P0: per-lane idx/deltas/prefetch + QK MFMA + e0 ----
    const int r0 = (w*2)*16 + lm, r1 = (w*2 + 1)*16 + lm;
    const int j0 = idx[(size_t)g0*16 + r0];
    const int j1 = idx[(size_t)g0*16 + r1];
    if (lq == 0) { s_idx[r0] = j0; s_idx[r1] = j1; }
    float4 dA, dB;
    {
        float4 cj0 = *(const float4*)&coords[(size_t)(bbase + j0)*4];
        float4 cn0 = *(const float4*)&coords[(size_t)(g0 + w*2)*4];
        dA = make_float4(cj0.x-cn0.x, cj0.y-cn0.y, cj0.z-cn0.z, cj0.w-cn0.w);
        float4 cj1 = *(const float4*)&coords[(size_t)(bbase + j1)*4];
        float4 cn1 = *(const float4*)&coords[(size_t)(g0 + w*2 + 1)*4];
        dB = make_float4(cj1.x-cn1.x, cj1.y-cn1.y, cj1.z-cn1.z, cj1.w-cn1.w);
    }
    // prefetch scores A-frag rows (row r0/r1, chunks ks*32+lq*8)
    bf16x8 pf[2][4];
    {
        const size_t rb0 = ((size_t)(bbase + j0)) << 7;
        const size_t rb1 = ((size_t)(bbase + j1)) << 7;
        #pragma unroll
        for (int ks = 0; ks < 4; ++ks) {
            pf[0][ks] = *(const bf16x8*)&xT[rb0 + ks*32 + lq*8];
            pf[1][ks] = *(const bf16x8*)&xT[rb1 + ks*32 + lq*8];
        }
    }
    // QK = A*X
    f32x4 accq[2] = {{0.f,0.f,0.f,0.f},{0.f,0.f,0.f,0.f}};
    {
        const bf16x8* Af = (const bf16x8*)Afrag;
        bf16x8 bfr[4];
        #pragma unroll
        for (int ks = 0; ks < 4; ++ks)
            bfr[ks] = *(const bf16x8*)&xT[(((size_t)(g0 + lmm)) << 7) + ks*32 + lq*8];
        #pragma unroll
        for (int mi = 0; mi < 2; ++mi) {
            const int ct = w*2 + mi;
            #pragma unroll
            for (int ks = 0; ks < 4; ++ks)
                accq[mi] = __builtin_amdgcn_mfma_f32_16x16x32_bf16(Af[(ct*4 + ks)*64 + l], bfr[ks], accq[mi], 0, 0, 0);
        }
    }
    // e0[n] = su2·x_n + d0b  (lanes 128..191: 8 per n)
    if (tid >= 128 && tid < 192) {
        int t = tid - 128, n = t >> 3, sub = t & 7, c0 = sub*16;
        uint4 x0 = *(const uint4*)&xT[(((size_t)(g0 + n)) << 7) + c0];
        uint4 x1 = *(const uint4*)&xT[(((size_t)(g0 + n)) << 7) + c0 + 8];
        float part = dot8(x0, &su2g[c0]) + dot8(x1, &su2g[c0+8]);
        part += __shfl_xor(part, 1);
        part += __shfl_xor(part, 2);
        part += __shfl_xor(part, 4);
        if (sub == 0) s_e0[n] = part + c_d0b;
    }
    // qk -> bf16 [n][c]
    if (lm < 8) {
        #pragma unroll
        for (int mi = 0; mi < 2; ++mi) {
            int c0 = (w*2 + mi)*16 + lq*4;
            float4 bA4 = *(const float4*)&bAg[c0];
            *(u64*)&s_qkb[lm][c0] = pack4(accq[mi][0] + bA4.x, accq[mi][1] + bA4.y,
                                          accq[mi][2] + bA4.z, accq[mi][3] + bA4.w);
        }
    }
    __syncthreads();   // B1: s_qkb, s_idx, s_e0, sBgT

    // ---- P1: H = relu(E*W1+b1) [all waves, E in regs] ; G = W2*QK [w0-1] ----
    {
        const bf16x8* W1f = (const bf16x8*)W1frag;
        bf16x8 w1f[2][4];
        #pragma unroll
        for (int nt = 0; nt < 2; ++nt)
            #pragma unroll
            for (int ks = 0; ks < 4; ++ks) w1f[nt][ks] = W1f[(nt*4 + ks)*64 + l];
        const float b1a = b1g[lm], b1b = b1g[16 + lm];
        #pragma unroll
        for (int mi = 0; mi < 2; ++mi) {
            const int mt = w*2 + mi;               // row = mt*16 + lm
            float4 d = mi ? dB : dA;
            bf16x8 ea[4];
            #pragma unroll
            for (int ksp = 0; ksp < 2; ++ksp) {
                #pragma unroll
                for (int jp = 0; jp < 4; ++jp) {
                    int f = ksp*32 + lq*8 + jp*2;
                    float4 ga = *(const float4*)sBgT[f];
                    float4 gb = *(const float4*)sBgT[f+1];
                    float p0 = d.x*ga.x + d.y*ga.y + d.z*ga.z + d.w*ga.w;
                    float p1 = d.x*gb.x + d.y*gb.y + d.z*gb.z + d.w*gb.w;
                    p0 -= floorf(p0); p1 -= floorf(p1);
                    ((u32*)&ea[ksp])[jp]   = (u32)f2b(__builtin_amdgcn_sinf(p0))
                                           | ((u32)f2b(__builtin_amdgcn_sinf(p1)) << 16);
                    ((u32*)&ea[ksp+2])[jp] = (u32)f2b(__builtin_amdgcn_cosf(p0))
                                           | ((u32)f2b(__builtin_amdgcn_cosf(p1)) << 16);
                }
            }
            f32x4 acch[2] = {{0.f,0.f,0.f,0.f},{0.f,0.f,0.f,0.f}};
            #pragma unroll
            for (int ks = 0; ks < 4; ++ks) {
                acch[0] = __builtin_amdgcn_mfma_f32_16x16x32_bf16(ea[ks], w1f[0][ks], acch[0], 0,0,0);
                acch[1] = __builtin_amdgcn_mfma_f32_16x16x32_bf16(ea[ks], w1f[1][ks], acch[1], 0,0,0);
            }
            #pragma unroll
            for (int r = 0; r < 4; ++r) {
                sH[mt*16 + lq*4 + r][lm]      = f2b(fmaxf(acch[0][r] + b1a, 0.f));
                sH[mt*16 + lq*4 + r][16 + lm] = f2b(fmaxf(acch[1][r] + b1b, 0.f));
            }
        }
    }
    if (w < 2) {
        const bf16x8* W2f = (const bf16x8*)W2frag;
        f32x4 accg = {0.f,0.f,0.f,0.f};
        #pragma unroll
        for (int ks = 0; ks < 4; ++ks) {
            bf16x8 bv = *(const bf16x8*)&s_qkb[lmm][ks*32 + lq*8];
            accg = __builtin_amdgcn_mfma_f32_16x16x32_bf16(W2f[(w*4 + ks)*64 + l], bv, accg, 0, 0, 0);
        }
        if (lm < 8) {
            int m0 = w*16 + lq*4;
            *(u64*)&s_gb[lm][m0] = pack4(accg[0], accg[1], accg[2], accg[3]);
        }
    }
    __syncthreads();   // B2: sH, s_gb

    // ---- P2: scores MFMA + in-wave softmax ----
    {
        bf16x8 bq4[5];
        #pragma unroll
        for (int ks = 0; ks < 4; ++ks) bq4[ks] = *(const bf16x8*)&s_qkb[lmm][ks*32 + lq*8];
        bq4[4] = *(const bf16x8*)&s_gb[lmm][lq*8];
        #pragma unroll
        for (int mi = 0; mi < 2; ++mi) {
            const int mt = w*2 + mi;               // n = mt, k = lm
            f32x4 acc = {0.f,0.f,0.f,0.f};
            #pragma unroll
            for (int ks = 0; ks < 4; ++ks)
                acc = __builtin_amdgcn_mfma_f32_16x16x32_bf16(pf[mi][ks], bq4[ks], acc, 0, 0, 0);
            {
                bf16x8 a = *(const bf16x8*)&sH[mt*16 + lm][lq*8];
                acc = __builtin_amdgcn_mfma_f32_16x16x32_bf16(a, bq4[4], acc, 0, 0, 0);
            }
            // softmax over 16 k: values live in 4 regs x 4 lanes (lq), col lm==mt
            float e0v = s_e0[mt];
            float s0 = (acc[0] + e0v) * inv_sqrtC;
            float s1 = (acc[1] + e0v) * inv_sqrtC;
            float s2 = (acc[2] + e0v) * inv_sqrtC;
            float s3 = (acc[3] + e0v) * inv_sqrtC;
            float mx = fmaxf(fmaxf(s0, s1), fmaxf(s2, s3));
            mx = fmaxf(mx, __shfl_xor(mx, 16));
            mx = fmaxf(mx, __shfl_xor(mx, 32));
            float e0_ = __expf(s0 - mx), e1_ = __expf(s1 - mx);
            float e2_ = __expf(s2 - mx), e3_ = __expf(s3 - mx);
            float sm = e0_ + e1_ + e2_ + e3_;
            sm += __shfl_xor(sm, 16);
            sm += __shfl_xor(sm, 32);
            if (lm == mt) {
                float inv = 1.f / sm;
                s_attn[mt][lq*4 + 0] = e0_ * inv;
                s_attn[mt][lq*4 + 1] = e1_ * inv;
                s_attn[mt][lq*4 + 2] = e2_ * inv;
                s_attn[mt][lq*4 + 3] = e3_ * inv;
            }
        }
    }
    __syncthreads();   // B3: s_attn

    // ---- P3: xbar -> s_xb bf16 [n][c] ; hbar -> sHbarT bf16 [n][m] ----
    {
        int n = tid >> 5, cs = tid & 31, c0 = cs*4;
        float a0[16];
        #pragma unroll
        for (int k = 0; k < 16; ++k) a0[k] = s_attn[n][k];
        float4 facc = make_float4(0.f, 0.f, 0.f, 0.f);
        #pragma unroll
        for (int k = 0; k < 16; ++k) {
            uint2 v = *(const uint2*)&xT[(((size_t)(bbase + s_idx[n*16 + k])) << 7) + c0];
            facc.x += a0[k]*bl(v.x); facc.y += a0[k]*bh(v.x);
            facc.z += a0[k]*bl(v.y); facc.w += a0[k]*bh(v.y);
        }
        *(u64*)&s_xb[n][c0] = pack4(facc.x, facc.y, facc.z, facc.w);
        float hacc = 0.f;
        #pragma unroll
        for (int k = 0; k < 16; ++k) hacc += a0[k] * b2f(sH[n*16 + k][cs]);
        sHbarT[n][cs] = f2b(hacc);
    }
    __syncthreads();   // B4: s_xb, sHbarT

    // ---- P4: OUT = Wov*xbar + Wovt2*hbar + bov2 -> global ----
    {
        const bf16x8* Wvf  = (const bf16x8*)Wovfrag;
        const bf16x8* Wt2f = (const bf16x8*)Wovt2frag;
        bf16x8 bx[4];
        #pragma unroll
        for (int ks = 0; ks < 4; ++ks) bx[ks] = *(const bf16x8*)&s_xb[lmm][ks*32 + lq*8];
        bf16x8 bh8 = *(const bf16x8*)&sHbarT[lmm][lq*8];
        #pragma unroll
        for (int mi = 0; mi < 2; ++mi) {
            const int ct = w*2 + mi;
            f32x4 acco = {0.f,0.f,0.f,0.f};
            #pragma unroll
            for (int ks = 0; ks < 4; ++ks)
                acco = __builtin_amdgcn_mfma_f32_16x16x32_bf16(Wvf[(ct*4 + ks)*64 + l], bx[ks], acco, 0, 0, 0);
            acco = __builtin_amdgcn_mfma_f32_16x16x32_bf16(Wt2f[ct*64 + l], bh8, acco, 0, 0, 0);
            if (lm < 8) {
                float4 bo4 = *(const float4*)&bov2g[ct*16 + lq*4];
                const float* bo4p = &bo4.x;
                #pragma unroll
                for (int r = 0; r < 4; ++r) {
                    int o = ct*16 + lq*4 + r;
                    out[(((size_t)(bsel*128 + o)) << 13) + n0 + lm] = acco[r] + bo4p[r];
                }
            }
        }
    }
}

// ---------------------------------------------------------------------------
extern "C" void kernel_launch(void* const* d_in, const int* in_sizes, int n_in,
                              void* d_out, int out_size, void* d_ws, size_t ws_size,
                              hipStream_t stream)
{
    const float* x      = (const float*)d_in[0];
    const float* coords = (const float*)d_in[1];
    const int*   idx    = (const int*)d_in[2];
    const float* Bg     = (const float*)d_in[3];
    const float* W1     = (const float*)d_in[4];
    const float* b1     = (const float*)d_in[5];
    const float* W2     = (const float*)d_in[6];
    const float* b2     = (const float*)d_in[7];
    const float* Wq     = (const float*)d_in[8];
    const float* bq     = (const float*)d_in[9];
    const float* Wk     = (const float*)d_in[10];
    const float* bk     = (const float*)d_in[11];
    const float* Wv     = (const float*)d_in[12];
    const float* bv     = (const float*)d_in[13];
    const float* Wo     = (const float*)d_in[14];
    const float* bo     = (const float*)d_in[15];
    float* out = (float*)d_out;

    char* ws = (char*)d_ws;
    u16*   Afrag    = (u16*)(ws);              // 32768 B
    u16*   Wovfrag  = (u16*)(ws + 32768);      // 32768 B
    u16*   W1frag   = (u16*)(ws + 65536);      // 8192 B
    u16*   W2frag   = (u16*)(ws + 73728);      // 8192 B
    u16*   Wovt2frag= (u16*)(ws + 81920);      // 8192 B
    float* bA       = (float*)(ws + 90112);    // 512 B
    float* su2      = (float*)(ws + 90624);    // 512 B
    float* bov2     = (float*)(ws + 91136);    // 512 B
    float* d0b      = (float*)(ws + 91648);    // 16 B
    u16*   xT       = (u16*)(ws + 94208);      // 4 MiB

    k_pt<<<2178, 512, 0, stream>>>(x, Wq, bq, Wk, bk, Wv, bv, Wo, bo, W1, W2, b2,
                                   Afrag, Wovfrag, W1frag, W2frag, Wovt2frag,
                                   bA, su2, bov2, d0b, xT);
    k_main<<<2048, 256, 0, stream>>>(xT, coords, idx, Bg, b1,
                                     Afrag, Wovfrag, W1frag, W2frag, Wovt2frag,
                                     bA, su2, bov2, d0b, out);
}

// Round 8
// 151.961 us; speedup vs baseline: 1.0503x; 1.0503x over previous
//
#include <hip/hip_runtime.h>

// LSGA fused kernel, round 8: round-7 algebra, round-6 register discipline.
//  - No register prefetch array (round-7 spill driver); scores loads Xnb rows
//    at use from the j0/j1 registers each lane holds.
//  - LDS padded into the (27.3,32.8] KB bin (sH stride 84) so the allocator
//    targets 5 blocks/CU -> ~102 VGPR budget (round-6 conditions: 88 VGPR,
//    no spill). Round 7's 18 KB LDS made it target 8 blocks -> 64 VGPR ->
//    119 MB scratch spill traffic.
//  - Kept: OUT = Wov·xbar + (Wov·W2^T)·hbar + bov2; e0 = su2·x_n + d0b;
//    in-wave softmax; 4 barriers; XCD swizzle (batch = blk&1).
//
// MFMA 16x16x32 lane mappings (verified rounds 3-7):
//   A-frag:  A[m = lane&15][k = (lane>>4)*8 + j]
//   B-frag:  B[k = (lane>>4)*8 + j][n = lane&15]
//   C/D:     col = lane&15, row = (lane>>4)*4 + reg

using u16 = unsigned short;
using u32 = unsigned int;
using u64 = unsigned long long;

typedef short bf16x8 __attribute__((ext_vector_type(8)));
typedef float f32x4  __attribute__((ext_vector_type(4)));

__device__ __forceinline__ float bl(u32 u) { return __uint_as_float(u << 16); }
__device__ __forceinline__ float bh(u32 u) { return __uint_as_float(u & 0xffff0000u); }
__device__ __forceinline__ float b2f(u16 u) { return __uint_as_float(((u32)u) << 16); }
__device__ __forceinline__ u16 f2b(float f) {
    u32 u = __float_as_uint(f);
    u32 r = u + 0x7fffu + ((u >> 16) & 1u);   // RNE
    return (u16)(r >> 16);
}
__device__ __forceinline__ float dot8(uint4 wv, const float* xp) {
    float4 a = *(const float4*)xp;
    float4 b = *(const float4*)(xp + 4);
    return bl(wv.x)*a.x + bh(wv.x)*a.y + bl(wv.y)*a.z + bh(wv.y)*a.w
         + bl(wv.z)*b.x + bh(wv.z)*b.y + bl(wv.w)*b.z + bh(wv.w)*b.w;
}
__device__ __forceinline__ u64 pack4(float a, float b, float c, float d) {
    return (u64)f2b(a) | ((u64)f2b(b) << 16) | ((u64)f2b(c) << 32) | ((u64)f2b(d) << 48);
}
// A-operand frag flat index for element [m][c] of a 128-col operand
__device__ __forceinline__ int fidxA(int m, int c) {
    return (((m >> 4)*4 + (c >> 5))*64 + ((c >> 3) & 3)*16 + (m & 15))*8 + (c & 7);
}

// ---------------------------------------------------------------------------
// Kernel 1 (merged): blocks 0..129 weight fuse/pack, 130..2177 transpose.
__global__ void __launch_bounds__(512)
k_pt(const float* __restrict__ x,
     const float* __restrict__ Wq, const float* __restrict__ bq,
     const float* __restrict__ Wk, const float* __restrict__ bk,
     const float* __restrict__ Wv, const float* __restrict__ bv,
     const float* __restrict__ Wo, const float* __restrict__ bo,
     const float* __restrict__ W1, const float* __restrict__ W2,
     const float* __restrict__ b2,
     u16* __restrict__ Afrag, u16* __restrict__ Wovfrag,
     u16* __restrict__ W1frag, u16* __restrict__ W2frag,
     u16* __restrict__ Wovt2frag,
     float* __restrict__ bA, float* __restrict__ su2,
     float* __restrict__ bov2, float* __restrict__ d0b,
     u16* __restrict__ xT)
{
    const int blk = blockIdx.x, tid = threadIdx.x;

    if (blk >= 130) {
        // ---- transpose x[b][c][n] -> xT[b][n][c] (bf16), 32x32 tiles ----
        __shared__ u16 tile[32][33];
        const int blk2 = blk - 130;
        const int b  = blk2 >> 10;
        const int ct = (blk2 >> 8) & 3;
        const int nt = blk2 & 255;
        const int tx = tid & 31, ty = tid >> 5;      // 32 x 16
        const size_t xb = (size_t)b * 128 * 8192;
        #pragma unroll
        for (int j = 0; j < 2; ++j) {
            int c = ct*32 + ty + j*16;
            tile[ty + j*16][tx] = f2b(x[xb + (size_t)c * 8192 + (size_t)(nt*32 + tx)]);
        }
        __syncthreads();
        #pragma unroll
        for (int j = 0; j < 2; ++j) {
            int n = nt*32 + ty + j*16;
            xT[xb + (size_t)n * 128 + (size_t)(ct*32 + tx)] = tile[tx][ty + j*16];
        }
        return;
    }

    const int i = tid & 127, p = tid >> 7;          // 4-way K-split
    if (blk < 128) {
        __shared__ float sWk[128], sWo[128];
        __shared__ float s_pA[4][128], s_pV[4][128];
        __shared__ float s_row[128];
        if (tid < 128) sWk[tid] = Wk[tid*128 + blk];
        else if (tid < 256) sWo[tid-128] = Wo[blk*128 + (tid-128)];
        __syncthreads();
        float accA = 0.f, accV = 0.f;
        #pragma unroll 8
        for (int o = p*32; o < p*32 + 32; ++o) {
            accA += sWk[o] * Wq[o*128 + i];
            accV += sWo[o] * Wv[o*128 + i];
        }
        s_pA[p][i] = accA; s_pV[p][i] = accV;
        __syncthreads();
        if (tid < 128) {
            float v = s_pA[0][tid] + s_pA[1][tid] + s_pA[2][tid] + s_pA[3][tid];
            Afrag[fidxA(blk, tid)] = f2b(v);
        } else if (tid < 256) {
            int ii = tid - 128;
            float v = s_pV[0][ii] + s_pV[1][ii] + s_pV[2][ii] + s_pV[3][ii];
            Wovfrag[fidxA(blk, ii)] = f2b(v);
            s_row[ii] = v;
        }
        __syncthreads();
        if (tid < 32) {
            // Wovt2[blk][m] = sum_c Wov[blk][c] * W2[m][c]; A-frag (K=32)
            float wv2 = 0.f;
            for (int c = 0; c < 128; ++c) wv2 += s_row[c] * W2[tid*128 + c];
            Wovt2frag[(((blk >> 4)*64) + (tid >> 3)*16 + (blk & 15))*8 + (tid & 7)] = f2b(wv2);
        } else if (tid == 32) {
            float rb2 = 0.f, a3 = 0.f;
            for (int c = 0; c < 128; ++c) rb2 += s_row[c] * b2[c];
            for (int o = 0; o < 128; ++o) a3 += sWo[o] * bv[o];
            bov2[blk] = rb2 + a3 + bo[blk];
        }
    } else if (blk == 128) {
        __shared__ float s_t[128];
        __shared__ float s_p1[4][128], s_p2[4][128];
        if (tid < 128) {
            float tt = 0.f;
            for (int c = 0; c < 128; ++c) tt += Wk[tid*128 + c] * b2[c];
            s_t[tid] = tt + bk[tid];          // t[o] + bk[o]
        }
        __syncthreads();
        float a1 = 0.f, a2 = 0.f;
        #pragma unroll 8
        for (int o = p*32; o < p*32 + 32; ++o) {
            a1 += Wk[o*128 + i] * bq[o];       // bA
            a2 += Wq[o*128 + i] * s_t[o];      // su2
        }
        s_p1[p][i] = a1; s_p2[p][i] = a2;
        __syncthreads();
        if (tid < 128) {
            bA[tid] = s_p1[0][tid] + s_p1[1][tid] + s_p1[2][tid] + s_p1[3][tid];
        } else if (tid < 256) {
            int ii = tid - 128;
            su2[ii] = s_p2[0][ii] + s_p2[1][ii] + s_p2[2][ii] + s_p2[3][ii];
        } else if (tid < 320) {
            int l = tid - 256;                 // one wave: d0b = bq·(t+bk)
            float part = bq[l]*s_t[l] + bq[l+64]*s_t[l+64];
            part += __shfl_xor(part, 1);
            part += __shfl_xor(part, 2);
            part += __shfl_xor(part, 4);
            part += __shfl_xor(part, 8);
            part += __shfl_xor(part, 16);
            part += __shfl_xor(part, 32);
            if (l == 0) *d0b = part;
        }
    } else {
        // blk == 129: fragment packs for W1 / W2
        for (int e = tid; e < 4096; e += 512) {
            int ii = e & 127, r2 = e >> 7;         // r2 in [0,32)
            {   // W1frag: B-operand of H=E*W1, elem B[k=ii][n=r2]
                int nt = r2 >> 4, lmm = r2 & 15;
                int ks = ii >> 5, q = (ii >> 3) & 3, j = ii & 7;
                W1frag[((nt*4 + ks)*64 + q*16 + lmm)*8 + j] = f2b(W1[ii*32 + r2]);
            }
            {   // W2frag: A-operand of G=W2*QK, elem A[m=r2][c=ii]
                int mt = r2 >> 4, lmm = r2 & 15;
                int ks = ii >> 5, q = (ii >> 3) & 3, j = ii & 7;
                W2frag[((mt*4 + ks)*64 + q*16 + lmm)*8 + j] = f2b(W2[r2*128 + ii]);
            }
        }
    }
}

// ---------------------------------------------------------------------------
// Kernel 2: fused main. Grid 2048 x 256; 8 n per block; 4 barriers; ~29 KB LDS
// (deliberately in the 5-blocks/CU bin so the allocator budgets ~102 VGPRs).
__global__ void __launch_bounds__(256, 4)
k_main(const u16* __restrict__ xT, const float* __restrict__ coords,
       const int* __restrict__ idx, const float* __restrict__ Bg,
       const float* __restrict__ b1g,
       const u16* __restrict__ Afrag, const u16* __restrict__ Wovfrag,
       const u16* __restrict__ W1frag, const u16* __restrict__ W2frag,
       const u16* __restrict__ Wovt2frag,
       const float* __restrict__ bAg, const float* __restrict__ su2g,
       const float* __restrict__ bov2g, const float* __restrict__ d0bg,
       float* __restrict__ out)
{
    // sH stride 84 (=168 B): 16-row A-frag reads hit 16 distinct banks, and
    // total LDS lands at ~29 KB -> 5 blocks/CU allocator target (see header).
    __shared__ __align__(16) u16   sH[128][84];      // H bf16 rows (n,k) x m
    __shared__ __align__(16) u16   s_qkb[8][136];    // qk bf16 [n][c]
    __shared__ __align__(16) u16   s_gb[8][40];      // g bf16 [n][m]
    __shared__ __align__(16) u16   s_xb[8][136];     // xbar bf16 [n][c]
    __shared__ __align__(16) u16   sHbarT[8][40];    // hbar bf16 [n][m]
    __shared__ float s_attn[8][17];
    __shared__ float s_e0[8];
    __shared__ __align__(16) float sBgT[64][4];
    __shared__ int s_idx[128];

    const int tid = threadIdx.x;
    const int w = tid >> 6, l = tid & 63, lm = l & 15, lq = l >> 4, lmm = lm & 7;
    // XCD swizzle: batch = blk&1, chunk = blk>>1
    const int bsel = blockIdx.x & 1;
    const int n0 = (blockIdx.x >> 1) * 8;
    const int g0 = (bsel << 13) + n0;
    const size_t bbase = ((size_t)bsel) << 13;
    const float inv_sqrtC = 0.08838834764831845f;

    sBgT[tid >> 2][tid & 3] = Bg[(tid & 3)*64 + (tid >> 2)];
    const float c_d0b = *d0bg;

    // ---- P0: per-lane idx/deltas + QK MFMA + e0 ----
    const int r0 = (w*2)*16 + lm, r1 = (w*2 + 1)*16 + lm;
    const int j0 = idx[(size_t)g0*16 + r0];
    const int j1 = idx[(size_t)g0*16 + r1];
    if (lq == 0) { s_idx[r0] = j0; s_idx[r1] = j1; }
    float4 dA, dB;
    {
        float4 cj0 = *(const float4*)&coords[(size_t)(bbase + j0)*4];
        float4 cn0 = *(const float4*)&coords[(size_t)(g0 + w*2)*4];
        dA = make_float4(cj0.x-cn0.x, cj0.y-cn0.y, cj0.z-cn0.z, cj0.w-cn0.w);
        float4 cj1 = *(const float4*)&coords[(size_t)(bbase + j1)*4];
        float4 cn1 = *(const float4*)&coords[(size_t)(g0 + w*2 + 1)*4];
        dB = make_float4(cj1.x-cn1.x, cj1.y-cn1.y, cj1.z-cn1.z, cj1.w-cn1.w);
    }
    // QK = A*X
    f32x4 accq[2] = {{0.f,0.f,0.f,0.f},{0.f,0.f,0.f,0.f}};
    {
        const bf16x8* Af = (const bf16x8*)Afrag;
        bf16x8 bfr[4];
        #pragma unroll
        for (int ks = 0; ks < 4; ++ks)
            bfr[ks] = *(const bf16x8*)&xT[(((size_t)(g0 + lmm)) << 7) + ks*32 + lq*8];
        #pragma unroll
        for (int mi = 0; mi < 2; ++mi) {
            const int ct = w*2 + mi;
            #pragma unroll
            for (int ks = 0; ks < 4; ++ks)
                accq[mi] = __builtin_amdgcn_mfma_f32_16x16x32_bf16(Af[(ct*4 + ks)*64 + l], bfr[ks], accq[mi], 0, 0, 0);
        }
    }
    // e0[n] = su2·x_n + d0b  (lanes 128..191: 8 per n)
    if (tid >= 128 && tid < 192) {
        int t = tid - 128, n = t >> 3, sub = t & 7, c0 = sub*16;
        uint4 x0 = *(const uint4*)&xT[(((size_t)(g0 + n)) << 7) + c0];
        uint4 x1 = *(const uint4*)&xT[(((size_t)(g0 + n)) << 7) + c0 + 8];
        float part = dot8(x0, &su2g[c0]) + dot8(x1, &su2g[c0+8]);
        part += __shfl_xor(part, 1);
        part += __shfl_xor(part, 2);
        part += __shfl_xor(part, 4);
        if (sub == 0) s_e0[n] = part + c_d0b;
    }
    // qk -> bf16 [n][c]
    if (lm < 8) {
        #pragma unroll
        for (int mi = 0; mi < 2; ++mi) {
            int c0 = (w*2 + mi)*16 + lq*4;
            float4 bA4 = *(const float4*)&bAg[c0];
            *(u64*)&s_qkb[lm][c0] = pack4(accq[mi][0] + bA4.x, accq[mi][1] + bA4.y,
                                          accq[mi][2] + bA4.z, accq[mi][3] + bA4.w);
        }
    }
    __syncthreads();   // B1: s_qkb, s_idx, s_e0, sBgT

    // ---- P1: H = relu(E*W1+b1) [all waves, E in regs] ; G = W2*QK [w0-1] ----
    {
        const bf16x8* W1f = (const bf16x8*)W1frag;
        bf16x8 w1f[2][4];
        #pragma unroll
        for (int nt = 0; nt < 2; ++nt)
            #pragma unroll
            for (int ks = 0; ks < 4; ++ks) w1f[nt][ks] = W1f[(nt*4 + ks)*64 + l];
        const float b1a = b1g[lm], b1b = b1g[16 + lm];
        #pragma unroll
        for (int mi = 0; mi < 2; ++mi) {
            const int mt = w*2 + mi;               // row = mt*16 + lm
            float4 d = mi ? dB : dA;
            bf16x8 ea[4];
            #pragma unroll
            for (int ksp = 0; ksp < 2; ++ksp) {
                #pragma unroll
                for (int jp = 0; jp < 4; ++jp) {
                    int f = ksp*32 + lq*8 + jp*2;
                    float4 ga = *(const float4*)sBgT[f];
                    float4 gb = *(const float4*)sBgT[f+1];
                    float p0 = d.x*ga.x + d.y*ga.y + d.z*ga.z + d.w*ga.w;
                    float p1 = d.x*gb.x + d.y*gb.y + d.z*gb.z + d.w*gb.w;
                    p0 -= floorf(p0); p1 -= floorf(p1);
                    ((u32*)&ea[ksp])[jp]   = (u32)f2b(__builtin_amdgcn_sinf(p0))
                                           | ((u32)f2b(__builtin_amdgcn_sinf(p1)) << 16);
                    ((u32*)&ea[ksp+2])[jp] = (u32)f2b(__builtin_amdgcn_cosf(p0))
                                           | ((u32)f2b(__builtin_amdgcn_cosf(p1)) << 16);
                }
            }
            f32x4 acch[2] = {{0.f,0.f,0.f,0.f},{0.f,0.f,0.f,0.f}};
            #pragma unroll
            for (int ks = 0; ks < 4; ++ks) {
                acch[0] = __builtin_amdgcn_mfma_f32_16x16x32_bf16(ea[ks], w1f[0][ks], acch[0], 0,0,0);
                acch[1] = __builtin_amdgcn_mfma_f32_16x16x32_bf16(ea[ks], w1f[1][ks], acch[1], 0,0,0);
            }
            #pragma unroll
            for (int r = 0; r < 4; ++r) {
                sH[mt*16 + lq*4 + r][lm]      = f2b(fmaxf(acch[0][r] + b1a, 0.f));
                sH[mt*16 + lq*4 + r][16 + lm] = f2b(fmaxf(acch[1][r] + b1b, 0.f));
            }
        }
    }
    if (w < 2) {
        const bf16x8* W2f = (const bf16x8*)W2frag;
        f32x4 accg = {0.f,0.f,0.f,0.f};
        #pragma unroll
        for (int ks = 0; ks < 4; ++ks) {
            bf16x8 bv = *(const bf16x8*)&s_qkb[lmm][ks*32 + lq*8];
            accg = __builtin_amdgcn_mfma_f32_16x16x32_bf16(W2f[(w*4 + ks)*64 + l], bv, accg, 0, 0, 0);
        }
        if (lm < 8) {
            int m0 = w*16 + lq*4;
            *(u64*)&s_gb[lm][m0] = pack4(accg[0], accg[1], accg[2], accg[3]);
        }
    }
    __syncthreads();   // B2: sH, s_gb

    // ---- P2: scores MFMA (Xnb rows loaded at use via j0/j1) + softmax ----
    {
        bf16x8 bq4[5];
        #pragma unroll
        for (int ks = 0; ks < 4; ++ks) bq4[ks] = *(const bf16x8*)&s_qkb[lmm][ks*32 + lq*8];
        bq4[4] = *(const bf16x8*)&s_gb[lmm][lq*8];
        #pragma unroll
        for (int mi = 0; mi < 2; ++mi) {
            const int mt = w*2 + mi;               // n = mt, k = lm
            const size_t rb = ((size_t)(bbase + (mi ? j1 : j0))) << 7;
            f32x4 acc = {0.f,0.f,0.f,0.f};
            #pragma unroll
            for (int ks = 0; ks < 4; ++ks) {
                bf16x8 a = *(const bf16x8*)&xT[rb + ks*32 + lq*8];
                acc = __builtin_amdgcn_mfma_f32_16x16x32_bf16(a, bq4[ks], acc, 0, 0, 0);
            }
            {
                bf16x8 a = *(const bf16x8*)&sH[mt*16 + lm][lq*8];
                acc = __builtin_amdgcn_mfma_f32_16x16x32_bf16(a, bq4[4], acc, 0, 0, 0);
            }
            // softmax over 16 k: values in 4 regs x 4 lanes (lq), col lm==mt
            float e0v = s_e0[mt];
            float s0 = (acc[0] + e0v) * inv_sqrtC;
            float s1 = (acc[1] + e0v) * inv_sqrtC;
            float s2 = (acc[2] + e0v) * inv_sqrtC;
            float s3 = (acc[3] + e0v) * inv_sqrtC;
            float mx = fmaxf(fmaxf(s0, s1), fmaxf(s2, s3));
            mx = fmaxf(mx, __shfl_xor(mx, 16));
            mx = fmaxf(mx, __shfl_xor(mx, 32));
            float e0_ = __expf(s0 - mx), e1_ = __expf(s1 - mx);
            float e2_ = __expf(s2 - mx), e3_ = __expf(s3 - mx);
            float sm = e0_ + e1_ + e2_ + e3_;
            sm += __shfl_xor(sm, 16);
            sm += __shfl_xor(sm, 32);
            if (lm == mt) {
                float inv = 1.f / sm;
                s_attn[mt][lq*4 + 0] = e0_ * inv;
                s_attn[mt][lq*4 + 1] = e1_ * inv;
                s_attn[mt][lq*4 + 2] = e2_ * inv;
                s_attn[mt][lq*4 + 3] = e3_ * inv;
            }
        }
    }
    __syncthreads();   // B3: s_attn

    // ---- P3: xbar -> s_xb bf16 [n][c] ; hbar -> sHbarT bf16 [n][m] ----
    {
        int n = tid >> 5, cs = tid & 31, c0 = cs*4;
        float a0[16];
        #pragma unroll
        for (int k = 0; k < 16; ++k) a0[k] = s_attn[n][k];
        float4 facc = make_float4(0.f, 0.f, 0.f, 0.f);
        #pragma unroll
        for (int k = 0; k < 16; ++k) {
            uint2 v = *(const uint2*)&xT[(((size_t)(bbase + s_idx[n*16 + k])) << 7) + c0];
            facc.x += a0[k]*bl(v.x); facc.y += a0[k]*bh(v.x);
            facc.z += a0[k]*bl(v.y); facc.w += a0[k]*bh(v.y);
        }
        *(u64*)&s_xb[n][c0] = pack4(facc.x, facc.y, facc.z, facc.w);
        float hacc = 0.f;
        #pragma unroll
        for (int k = 0; k < 16; ++k) hacc += a0[k] * b2f(sH[n*16 + k][cs]);
        sHbarT[n][cs] = f2b(hacc);
    }
    __syncthreads();   // B4: s_xb, sHbarT

    // ---- P4: OUT = Wov*xbar + Wovt2*hbar + bov2 -> global ----
    {
        const bf16x8* Wvf  = (const bf16x8*)Wovfrag;
        const bf16x8* Wt2f = (const bf16x8*)Wovt2frag;
        bf16x8 bx[4];
        #pragma unroll
        for (int ks = 0; ks < 4; ++ks) bx[ks] = *(const bf16x8*)&s_xb[lmm][ks*32 + lq*8];
        bf16x8 bh8 = *(const bf16x8*)&sHbarT[lmm][lq*8];
        #pragma unroll
        for (int mi = 0; mi < 2; ++mi) {
            const int ct = w*2 + mi;
            f32x4 acco = {0.f,0.f,0.f,0.f};
            #pragma unroll
            for (int ks = 0; ks < 4; ++ks)
                acco = __builtin_amdgcn_mfma_f32_16x16x32_bf16(Wvf[(ct*4 + ks)*64 + l], bx[ks], acco, 0, 0, 0);
            acco = __builtin_amdgcn_mfma_f32_16x16x32_bf16(Wt2f[ct*64 + l], bh8, acco, 0, 0, 0);
            if (lm < 8) {
                float4 bo4 = *(const float4*)&bov2g[ct*16 + lq*4];
                const float* bo4p = &bo4.x;
                #pragma unroll
                for (int r = 0; r < 4; ++r) {
                    int o = ct*16 + lq*4 + r;
                    out[(((size_t)(bsel*128 + o)) << 13) + n0 + lm] = acco[r] + bo4p[r];
                }
            }
        }
    }
}

// ---------------------------------------------------------------------------
extern "C" void kernel_launch(void* const* d_in, const int* in_sizes, int n_in,
                              void* d_out, int out_size, void* d_ws, size_t ws_size,
                              hipStream_t stream)
{
    const float* x      = (const float*)d_in[0];
    const float* coords = (const float*)d_in[1];
    const int*   idx    = (const int*)d_in[2];
    const float* Bg     = (const float*)d_in[3];
    const float* W1     = (const float*)d_in[4];
    const float* b1     = (const float*)d_in[5];
    const float* W2     = (const float*)d_in[6];
    const float* b2     = (const float*)d_in[7];
    const float* Wq     = (const float*)d_in[8];
    const float* bq     = (const float*)d_in[9];
    const float* Wk     = (const float*)d_in[10];
    const float* bk     = (const float*)d_in[11];
    const float* Wv     = (const float*)d_in[12];
    const float* bv     = (const float*)d_in[13];
    const float* Wo     = (const float*)d_in[14];
    const float* bo     = (const float*)d_in[15];
    float* out = (float*)d_out;

    char* ws = (char*)d_ws;
    u16*   Afrag    = (u16*)(ws);              // 32768 B
    u16*   Wovfrag  = (u16*)(ws + 32768);      // 32768 B
    u16*   W1frag   = (u16*)(ws + 65536);      // 8192 B
    u16*   W2frag   = (u16*)(ws + 73728);      // 8192 B
    u16*   Wovt2frag= (u16*)(ws + 81920);      // 8192 B
    float* bA       = (float*)(ws + 90112);    // 512 B
    float* su2      = (float*)(ws + 90624);    // 512 B
    float* bov2     = (float*)(ws + 91136);    // 512 B
    float* d0b      = (float*)(ws + 91648);    // 16 B
    u16*   xT       = (u16*)(ws + 94208);      // 4 MiB

    k_pt<<<2178, 512, 0, stream>>>(x, Wq, bq, Wk, bk, Wv, bv, Wo, bo, W1, W2, b2,
                                   Afrag, Wovfrag, W1frag, W2frag, Wovt2frag,
                                   bA, su2, bov2, d0b, xT);
    k_main<<<2048, 256, 0, stream>>>(xT, coords, idx, Bg, b1,
                                     Afrag, Wovfrag, W1frag, W2frag, Wovt2frag,
                                     bA, su2, bov2, d0b, out);
}

// Round 9
// 142.264 us; speedup vs baseline: 1.1219x; 1.0682x over previous
//
#include <hip/hip_runtime.h>

// LSGA fused kernel, round 9 = round 8 with single-arg __launch_bounds__.
// EMPIRICAL LAW (r5/r7/r8 vs r2/r3/r4): two-arg __launch_bounds__(256,N) on
// this toolchain caps VGPRs at 512/(2N) (N=4 -> 64, N=5 -> 48) and FORCES
// scratch spill (86-208 MB WRITE_SIZE). Single-arg never spills. So: control
// occupancy via LDS + natural pressure only; never pass the 2nd arg.
//
// Algebra (verified, absmax 3.9e-3):
//   qk   = A·x_n + bA;  A = Wk^T Wq
//   s[k] = (qk·x_nb[k] + h[k]·g + e0)/sqrt(C),  e0 = su2·x_n + d0b
//   attn = softmax_k(s)
//   OUT  = Wov·xbar + (Wov·W2^T)·hbar + bov2
//
// MFMA 16x16x32 lane mappings (verified rounds 3-8):
//   A-frag:  A[m = lane&15][k = (lane>>4)*8 + j]
//   B-frag:  B[k = (lane>>4)*8 + j][n = lane&15]
//   C/D:     col = lane&15, row = (lane>>4)*4 + reg

using u16 = unsigned short;
using u32 = unsigned int;
using u64 = unsigned long long;

typedef short bf16x8 __attribute__((ext_vector_type(8)));
typedef float f32x4  __attribute__((ext_vector_type(4)));

__device__ __forceinline__ float bl(u32 u) { return __uint_as_float(u << 16); }
__device__ __forceinline__ float bh(u32 u) { return __uint_as_float(u & 0xffff0000u); }
__device__ __forceinline__ float b2f(u16 u) { return __uint_as_float(((u32)u) << 16); }
__device__ __forceinline__ u16 f2b(float f) {
    u32 u = __float_as_uint(f);
    u32 r = u + 0x7fffu + ((u >> 16) & 1u);   // RNE
    return (u16)(r >> 16);
}
__device__ __forceinline__ float dot8(uint4 wv, const float* xp) {
    float4 a = *(const float4*)xp;
    float4 b = *(const float4*)(xp + 4);
    return bl(wv.x)*a.x + bh(wv.x)*a.y + bl(wv.y)*a.z + bh(wv.y)*a.w
         + bl(wv.z)*b.x + bh(wv.z)*b.y + bl(wv.w)*b.z + bh(wv.w)*b.w;
}
__device__ __forceinline__ u64 pack4(float a, float b, float c, float d) {
    return (u64)f2b(a) | ((u64)f2b(b) << 16) | ((u64)f2b(c) << 32) | ((u64)f2b(d) << 48);
}
// A-operand frag flat index for element [m][c] of a 128-col operand
__device__ __forceinline__ int fidxA(int m, int c) {
    return (((m >> 4)*4 + (c >> 5))*64 + ((c >> 3) & 3)*16 + (m & 15))*8 + (c & 7);
}

// ---------------------------------------------------------------------------
// Kernel 1 (merged): blocks 0..129 weight fuse/pack, 130..2177 transpose.
__global__ void __launch_bounds__(512)
k_pt(const float* __restrict__ x,
     const float* __restrict__ Wq, const float* __restrict__ bq,
     const float* __restrict__ Wk, const float* __restrict__ bk,
     const float* __restrict__ Wv, const float* __restrict__ bv,
     const float* __restrict__ Wo, const float* __restrict__ bo,
     const float* __restrict__ W1, const float* __restrict__ W2,
     const float* __restrict__ b2,
     u16* __restrict__ Afrag, u16* __restrict__ Wovfrag,
     u16* __restrict__ W1frag, u16* __restrict__ W2frag,
     u16* __restrict__ Wovt2frag,
     float* __restrict__ bA, float* __restrict__ su2,
     float* __restrict__ bov2, float* __restrict__ d0b,
     u16* __restrict__ xT)
{
    const int blk = blockIdx.x, tid = threadIdx.x;

    if (blk >= 130) {
        // ---- transpose x[b][c][n] -> xT[b][n][c] (bf16), 32x32 tiles ----
        __shared__ u16 tile[32][33];
        const int blk2 = blk - 130;
        const int b  = blk2 >> 10;
        const int ct = (blk2 >> 8) & 3;
        const int nt = blk2 & 255;
        const int tx = tid & 31, ty = tid >> 5;      // 32 x 16
        const size_t xb = (size_t)b * 128 * 8192;
        #pragma unroll
        for (int j = 0; j < 2; ++j) {
            int c = ct*32 + ty + j*16;
            tile[ty + j*16][tx] = f2b(x[xb + (size_t)c * 8192 + (size_t)(nt*32 + tx)]);
        }
        __syncthreads();
        #pragma unroll
        for (int j = 0; j < 2; ++j) {
            int n = nt*32 + ty + j*16;
            xT[xb + (size_t)n * 128 + (size_t)(ct*32 + tx)] = tile[tx][ty + j*16];
        }
        return;
    }

    const int i = tid & 127, p = tid >> 7;          // 4-way K-split
    if (blk < 128) {
        __shared__ float sWk[128], sWo[128];
        __shared__ float s_pA[4][128], s_pV[4][128];
        __shared__ float s_row[128];
        if (tid < 128) sWk[tid] = Wk[tid*128 + blk];
        else if (tid < 256) sWo[tid-128] = Wo[blk*128 + (tid-128)];
        __syncthreads();
        float accA = 0.f, accV = 0.f;
        #pragma unroll 8
        for (int o = p*32; o < p*32 + 32; ++o) {
            accA += sWk[o] * Wq[o*128 + i];
            accV += sWo[o] * Wv[o*128 + i];
        }
        s_pA[p][i] = accA; s_pV[p][i] = accV;
        __syncthreads();
        if (tid < 128) {
            float v = s_pA[0][tid] + s_pA[1][tid] + s_pA[2][tid] + s_pA[3][tid];
            Afrag[fidxA(blk, tid)] = f2b(v);
        } else if (tid < 256) {
            int ii = tid - 128;
            float v = s_pV[0][ii] + s_pV[1][ii] + s_pV[2][ii] + s_pV[3][ii];
            Wovfrag[fidxA(blk, ii)] = f2b(v);
            s_row[ii] = v;
        }
        __syncthreads();
        if (tid < 32) {
            // Wovt2[blk][m] = sum_c Wov[blk][c] * W2[m][c]; A-frag (K=32)
            float wv2 = 0.f;
            for (int c = 0; c < 128; ++c) wv2 += s_row[c] * W2[tid*128 + c];
            Wovt2frag[(((blk >> 4)*64) + (tid >> 3)*16 + (blk & 15))*8 + (tid & 7)] = f2b(wv2);
        } else if (tid == 32) {
            float rb2 = 0.f, a3 = 0.f;
            for (int c = 0; c < 128; ++c) rb2 += s_row[c] * b2[c];
            for (int o = 0; o < 128; ++o) a3 += sWo[o] * bv[o];
            bov2[blk] = rb2 + a3 + bo[blk];
        }
    } else if (blk == 128) {
        __shared__ float s_t[128];
        __shared__ float s_p1[4][128], s_p2[4][128];
        if (tid < 128) {
            float tt = 0.f;
            for (int c = 0; c < 128; ++c) tt += Wk[tid*128 + c] * b2[c];
            s_t[tid] = tt + bk[tid];          // t[o] + bk[o]
        }
        __syncthreads();
        float a1 = 0.f, a2 = 0.f;
        #pragma unroll 8
        for (int o = p*32; o < p*32 + 32; ++o) {
            a1 += Wk[o*128 + i] * bq[o];       // bA
            a2 += Wq[o*128 + i] * s_t[o];      // su2
        }
        s_p1[p][i] = a1; s_p2[p][i] = a2;
        __syncthreads();
        if (tid < 128) {
            bA[tid] = s_p1[0][tid] + s_p1[1][tid] + s_p1[2][tid] + s_p1[3][tid];
        } else if (tid < 256) {
            int ii = tid - 128;
            su2[ii] = s_p2[0][ii] + s_p2[1][ii] + s_p2[2][ii] + s_p2[3][ii];
        } else if (tid < 320) {
            int l = tid - 256;                 // one wave: d0b = bq·(t+bk)
            float part = bq[l]*s_t[l] + bq[l+64]*s_t[l+64];
            part += __shfl_xor(part, 1);
            part += __shfl_xor(part, 2);
            part += __shfl_xor(part, 4);
            part += __shfl_xor(part, 8);
            part += __shfl_xor(part, 16);
            part += __shfl_xor(part, 32);
            if (l == 0) *d0b = part;
        }
    } else {
        // blk == 129: fragment packs for W1 / W2
        for (int e = tid; e < 4096; e += 512) {
            int ii = e & 127, r2 = e >> 7;         // r2 in [0,32)
            {   // W1frag: B-operand of H=E*W1, elem B[k=ii][n=r2]
                int nt = r2 >> 4, lmm = r2 & 15;
                int ks = ii >> 5, q = (ii >> 3) & 3, j = ii & 7;
                W1frag[((nt*4 + ks)*64 + q*16 + lmm)*8 + j] = f2b(W1[ii*32 + r2]);
            }
            {   // W2frag: A-operand of G=W2*QK, elem A[m=r2][c=ii]
                int mt = r2 >> 4, lmm = r2 & 15;
                int ks = ii >> 5, q = (ii >> 3) & 3, j = ii & 7;
                W2frag[((mt*4 + ks)*64 + q*16 + lmm)*8 + j] = f2b(W2[r2*128 + ii]);
            }
        }
    }
}

// ---------------------------------------------------------------------------
// Kernel 2: fused main. Grid 2048 x 256; 8 n per block; 4 barriers; ~29 KB LDS.
// Single-arg launch bounds: natural VGPR allocation, no forced spill.
__global__ void __launch_bounds__(256)
k_main(const u16* __restrict__ xT, const float* __restrict__ coords,
       const int* __restrict__ idx, const float* __restrict__ Bg,
       const float* __restrict__ b1g,
       const u16* __restrict__ Afrag, const u16* __restrict__ Wovfrag,
       const u16* __restrict__ W1frag, const u16* __restrict__ W2frag,
       const u16* __restrict__ Wovt2frag,
       const float* __restrict__ bAg, const float* __restrict__ su2g,
       const float* __restrict__ bov2g, const float* __restrict__ d0bg,
       float* __restrict__ out)
{
    // sH stride 84 (=168 B): 16-row A-frag reads spread 16 distinct banks.
    __shared__ __align__(16) u16   sH[128][84];      // H bf16 rows (n,k) x m
    __shared__ __align__(16) u16   s_qkb[8][136];    // qk bf16 [n][c]
    __shared__ __align__(16) u16   s_gb[8][40];      // g bf16 [n][m]
    __shared__ __align__(16) u16   s_xb[8][136];     // xbar bf16 [n][c]
    __shared__ __align__(16) u16   sHbarT[8][40];    // hbar bf16 [n][m]
    __shared__ float s_attn[8][17];
    __shared__ float s_e0[8];
    __shared__ __align__(16) float sBgT[64][4];
    __shared__ int s_idx[128];

    const int tid = threadIdx.x;
    const int w = tid >> 6, l = tid & 63, lm = l & 15, lq = l >> 4, lmm = lm & 7;
    // XCD swizzle: batch = blk&1, chunk = blk>>1
    const int bsel = blockIdx.x & 1;
    const int n0 = (blockIdx.x >> 1) * 8;
    const int g0 = (bsel << 13) + n0;
    const size_t bbase = ((size_t)bsel) << 13;
    const float inv_sqrtC = 0.08838834764831845f;

    sBgT[tid >> 2][tid & 3] = Bg[(tid & 3)*64 + (tid >> 2)];
    const float c_d0b = *d0bg;

    // ---- P0: per-lane idx/deltas + QK MFMA + e0 ----
    const int r0 = (w*2)*16 + lm, r1 = (w*2 + 1)*16 + lm;
    const int j0 = idx[(size_t)g0*16 + r0];
    const int j1 = idx[(size_t)g0*16 + r1];
    if (lq == 0) { s_idx[r0] = j0; s_idx[r1] = j1; }
    float4 dA, dB;
    {
        float4 cj0 = *(const float4*)&coords[(size_t)(bbase + j0)*4];
        float4 cn0 = *(const float4*)&coords[(size_t)(g0 + w*2)*4];
        dA = make_float4(cj0.x-cn0.x, cj0.y-cn0.y, cj0.z-cn0.z, cj0.w-cn0.w);
        float4 cj1 = *(const float4*)&coords[(size_t)(bbase + j1)*4];
        float4 cn1 = *(const float4*)&coords[(size_t)(g0 + w*2 + 1)*4];
        dB = make_float4(cj1.x-cn1.x, cj1.y-cn1.y, cj1.z-cn1.z, cj1.w-cn1.w);
    }
    // QK = A*X
    f32x4 accq[2] = {{0.f,0.f,0.f,0.f},{0.f,0.f,0.f,0.f}};
    {
        const bf16x8* Af = (const bf16x8*)Afrag;
        bf16x8 bfr[4];
        #pragma unroll
        for (int ks = 0; ks < 4; ++ks)
            bfr[ks] = *(const bf16x8*)&xT[(((size_t)(g0 + lmm)) << 7) + ks*32 + lq*8];
        #pragma unroll
        for (int mi = 0; mi < 2; ++mi) {
            const int ct = w*2 + mi;
            #pragma unroll
            for (int ks = 0; ks < 4; ++ks)
                accq[mi] = __builtin_amdgcn_mfma_f32_16x16x32_bf16(Af[(ct*4 + ks)*64 + l], bfr[ks], accq[mi], 0, 0, 0);
        }
    }
    // e0[n] = su2·x_n + d0b  (lanes 128..191: 8 per n)
    if (tid >= 128 && tid < 192) {
        int t = tid - 128, n = t >> 3, sub = t & 7, c0 = sub*16;
        uint4 x0 = *(const uint4*)&xT[(((size_t)(g0 + n)) << 7) + c0];
        uint4 x1 = *(const uint4*)&xT[(((size_t)(g0 + n)) << 7) + c0 + 8];
        float part = dot8(x0, &su2g[c0]) + dot8(x1, &su2g[c0+8]);
        part += __shfl_xor(part, 1);
        part += __shfl_xor(part, 2);
        part += __shfl_xor(part, 4);
        if (sub == 0) s_e0[n] = part + c_d0b;
    }
    // qk -> bf16 [n][c]
    if (lm < 8) {
        #pragma unroll
        for (int mi = 0; mi < 2; ++mi) {
            int c0 = (w*2 + mi)*16 + lq*4;
            float4 bA4 = *(const float4*)&bAg[c0];
            *(u64*)&s_qkb[lm][c0] = pack4(accq[mi][0] + bA4.x, accq[mi][1] + bA4.y,
                                          accq[mi][2] + bA4.z, accq[mi][3] + bA4.w);
        }
    }
    __syncthreads();   // B1: s_qkb, s_idx, s_e0, sBgT

    // ---- P1: H = relu(E*W1+b1) [all waves, E in regs] ; G = W2*QK [w0-1] ----
    {
        const bf16x8* W1f = (const bf16x8*)W1frag;
        bf16x8 w1f[2][4];
        #pragma unroll
        for (int nt = 0; nt < 2; ++nt)
            #pragma unroll
            for (int ks = 0; ks < 4; ++ks) w1f[nt][ks] = W1f[(nt*4 + ks)*64 + l];
        const float b1a = b1g[lm], b1b = b1g[16 + lm];
        #pragma unroll
        for (int mi = 0; mi < 2; ++mi) {
            const int mt = w*2 + mi;               // row = mt*16 + lm
            float4 d = mi ? dB : dA;
            bf16x8 ea[4];
            #pragma unroll
            for (int ksp = 0; ksp < 2; ++ksp) {
                #pragma unroll
                for (int jp = 0; jp < 4; ++jp) {
                    int f = ksp*32 + lq*8 + jp*2;
                    float4 ga = *(const float4*)sBgT[f];
                    float4 gb = *(const float4*)sBgT[f+1];
                    float p0 = d.x*ga.x + d.y*ga.y + d.z*ga.z + d.w*ga.w;
                    float p1 = d.x*gb.x + d.y*gb.y + d.z*gb.z + d.w*gb.w;
                    p0 -= floorf(p0); p1 -= floorf(p1);
                    ((u32*)&ea[ksp])[jp]   = (u32)f2b(__builtin_amdgcn_sinf(p0))
                                           | ((u32)f2b(__builtin_amdgcn_sinf(p1)) << 16);
                    ((u32*)&ea[ksp+2])[jp] = (u32)f2b(__builtin_amdgcn_cosf(p0))
                                           | ((u32)f2b(__builtin_amdgcn_cosf(p1)) << 16);
                }
            }
            f32x4 acch[2] = {{0.f,0.f,0.f,0.f},{0.f,0.f,0.f,0.f}};
            #pragma unroll
            for (int ks = 0; ks < 4; ++ks) {
                acch[0] = __builtin_amdgcn_mfma_f32_16x16x32_bf16(ea[ks], w1f[0][ks], acch[0], 0,0,0);
                acch[1] = __builtin_amdgcn_mfma_f32_16x16x32_bf16(ea[ks], w1f[1][ks], acch[1], 0,0,0);
            }
            #pragma unroll
            for (int r = 0; r < 4; ++r) {
                sH[mt*16 + lq*4 + r][lm]      = f2b(fmaxf(acch[0][r] + b1a, 0.f));
                sH[mt*16 + lq*4 + r][16 + lm] = f2b(fmaxf(acch[1][r] + b1b, 0.f));
            }
        }
    }
    if (w < 2) {
        const bf16x8* W2f = (const bf16x8*)W2frag;
        f32x4 accg = {0.f,0.f,0.f,0.f};
        #pragma unroll
        for (int ks = 0; ks < 4; ++ks) {
            bf16x8 bv = *(const bf16x8*)&s_qkb[lmm][ks*32 + lq*8];
            accg = __builtin_amdgcn_mfma_f32_16x16x32_bf16(W2f[(w*4 + ks)*64 + l], bv, accg, 0, 0, 0);
        }
        if (lm < 8) {
            int m0 = w*16 + lq*4;
            *(u64*)&s_gb[lm][m0] = pack4(accg[0], accg[1], accg[2], accg[3]);
        }
    }
    __syncthreads();   // B2: sH, s_gb

    // ---- P2: scores MFMA (Xnb rows loaded at use via j0/j1) + softmax ----
    {
        bf16x8 bq4[5];
        #pragma unroll
        for (int ks = 0; ks < 4; ++ks) bq4[ks] = *(const bf16x8*)&s_qkb[lmm][ks*32 + lq*8];
        bq4[4] = *(const bf16x8*)&s_gb[lmm][lq*8];
        #pragma unroll
        for (int mi = 0; mi < 2; ++mi) {
            const int mt = w*2 + mi;               // n = mt, k = lm
            const size_t rb = ((size_t)(bbase + (mi ? j1 : j0))) << 7;
            f32x4 acc = {0.f,0.f,0.f,0.f};
            #pragma unroll
            for (int ks = 0; ks < 4; ++ks) {
                bf16x8 a = *(const bf16x8*)&xT[rb + ks*32 + lq*8];
                acc = __builtin_amdgcn_mfma_f32_16x16x32_bf16(a, bq4[ks], acc, 0, 0, 0);
            }
            {
                bf16x8 a = *(const bf16x8*)&sH[mt*16 + lm][lq*8];
                acc = __builtin_amdgcn_mfma_f32_16x16x32_bf16(a, bq4[4], acc, 0, 0, 0);
            }
            // softmax over 16 k: values in 4 regs x 4 lanes (lq), col lm==mt
            float e0v = s_e0[mt];
            float s0 = (acc[0] + e0v) * inv_sqrtC;
            float s1 = (acc[1] + e0v) * inv_sqrtC;
            float s2 = (acc[2] + e0v) * inv_sqrtC;
            float s3 = (acc[3] + e0v) * inv_sqrtC;
            float mx = fmaxf(fmaxf(s0, s1), fmaxf(s2, s3));
            mx = fmaxf(mx, __shfl_xor(mx, 16));
            mx = fmaxf(mx, __shfl_xor(mx, 32));
            float e0_ = __expf(s0 - mx), e1_ = __expf(s1 - mx);
            float e2_ = __expf(s2 - mx), e3_ = __expf(s3 - mx);
            float sm = e0_ + e1_ + e2_ + e3_;
            sm += __shfl_xor(sm, 16);
            sm += __shfl_xor(sm, 32);
            if (lm == mt) {
                float inv = 1.f / sm;
                s_attn[mt][lq*4 + 0] = e0_ * inv;
                s_attn[mt][lq*4 + 1] = e1_ * inv;
                s_attn[mt][lq*4 + 2] = e2_ * inv;
                s_attn[mt][lq*4 + 3] = e3_ * inv;
            }
        }
    }
    __syncthreads();   // B3: s_attn

    // ---- P3: xbar -> s_xb bf16 [n][c] ; hbar -> sHbarT bf16 [n][m] ----
    {
        int n = tid >> 5, cs = tid & 31, c0 = cs*4;
        float a0[16];
        #pragma unroll
        for (int k = 0; k < 16; ++k) a0[k] = s_attn[n][k];
        float4 facc = make_float4(0.f, 0.f, 0.f, 0.f);
        #pragma unroll
        for (int k = 0; k < 16; ++k) {
            uint2 v = *(const uint2*)&xT[(((size_t)(bbase + s_idx[n*16 + k])) << 7) + c0];
            facc.x += a0[k]*bl(v.x); facc.y += a0[k]*bh(v.x);
            facc.z += a0[k]*bl(v.y); facc.w += a0[k]*bh(v.y);
        }
        *(u64*)&s_xb[n][c0] = pack4(facc.x, facc.y, facc.z, facc.w);
        float hacc = 0.f;
        #pragma unroll
        for (int k = 0; k < 16; ++k) hacc += a0[k] * b2f(sH[n*16 + k][cs]);
        sHbarT[n][cs] = f2b(hacc);
    }
    __syncthreads();   // B4: s_xb, sHbarT

    // ---- P4: OUT = Wov*xbar + Wovt2*hbar + bov2 -> global ----
    {
        const bf16x8* Wvf  = (const bf16x8*)Wovfrag;
        const bf16x8* Wt2f = (const bf16x8*)Wovt2frag;
        bf16x8 bx[4];
        #pragma unroll
        for (int ks = 0; ks < 4; ++ks) bx[ks] = *(const bf16x8*)&s_xb[lmm][ks*32 + lq*8];
        bf16x8 bh8 = *(const bf16x8*)&sHbarT[lmm][lq*8];
        #pragma unroll
        for (int mi = 0; mi < 2; ++mi) {
            const int ct = w*2 + mi;
            f32x4 acco = {0.f,0.f,0.f,0.f};
            #pragma unroll
            for (int ks = 0; ks < 4; ++ks)
                acco = __builtin_amdgcn_mfma_f32_16x16x32_bf16(Wvf[(ct*4 + ks)*64 + l], bx[ks], acco, 0, 0, 0);
            acco = __builtin_amdgcn_mfma_f32_16x16x32_bf16(Wt2f[ct*64 + l], bh8, acco, 0, 0, 0);
            if (lm < 8) {
                float4 bo4 = *(const float4*)&bov2g[ct*16 + lq*4];
                const float* bo4p = &bo4.x;
                #pragma unroll
                for (int r = 0; r < 4; ++r) {
                    int o = ct*16 + lq*4 + r;
                    out[(((size_t)(bsel*128 + o)) << 13) + n0 + lm] = acco[r] + bo4p[r];
                }
            }
        }
    }
}

// ---------------------------------------------------------------------------
extern "C" void kernel_launch(void* const* d_in, const int* in_sizes, int n_in,
                              void* d_out, int out_size, void* d_ws, size_t ws_size,
                              hipStream_t stream)
{
    const float* x      = (const float*)d_in[0];
    const float* coords = (const float*)d_in[1];
    const int*   idx    = (const int*)d_in[2];
    const float* Bg     = (const float*)d_in[3];
    const float* W1     = (const float*)d_in[4];
    const float* b1     = (const float*)d_in[5];
    const float* W2     = (const float*)d_in[6];
    const float* b2     = (const float*)d_in[7];
    const float* Wq     = (const float*)d_in[8];
    const float* bq     = (const float*)d_in[9];
    const float* Wk     = (const float*)d_in[10];
    const float* bk     = (const float*)d_in[11];
    const float* Wv     = (const float*)d_in[12];
    const float* bv     = (const float*)d_in[13];
    const float* Wo     = (const float*)d_in[14];
    const float* bo     = (const float*)d_in[15];
    float* out = (float*)d_out;

    char* ws = (char*)d_ws;
    u16*   Afrag    = (u16*)(ws);              // 32768 B
    u16*   Wovfrag  = (u16*)(ws + 32768);      // 32768 B
    u16*   W1frag   = (u16*)(ws + 65536);      // 8192 B
    u16*   W2frag   = (u16*)(ws + 73728);      // 8192 B
    u16*   Wovt2frag= (u16*)(ws + 81920);      // 8192 B
    float* bA       = (float*)(ws + 90112);    // 512 B
    float* su2      = (float*)(ws + 90624);    // 512 B
    float* bov2     = (float*)(ws + 91136);    // 512 B
    float* d0b      = (float*)(ws + 91648);    // 16 B
    u16*   xT       = (u16*)(ws + 94208);      // 4 MiB

    k_pt<<<2178, 512, 0, stream>>>(x, Wq, bq, Wk, bk, Wv, bv, Wo, bo, W1, W2, b2,
                                   Afrag, Wovfrag, W1frag, W2frag, Wovt2frag,
                                   bA, su2, bov2, d0b, xT);
    k_main<<<2048, 256, 0, stream>>>(xT, coords, idx, Bg, b1,
                                     Afrag, Wovfrag, W1frag, W2frag, Wovt2frag,
                                     bA, su2, bov2, d0b, out);
}